// Round 2
// 1207.213 us; speedup vs baseline: 1.0031x; 1.0031x over previous
//
#include <hip/hip_runtime.h>
#include <cstdint>

#define T_TOKENS 8192
#define DMODEL 1024
#define DFF 4096
#define NEXP 8

typedef _Float16 f16x8 __attribute__((ext_vector_type(8)));
typedef float f32x4 __attribute__((ext_vector_type(4)));
using u16 = unsigned short;

__device__ __forceinline__ u16 f2h(float f) {
  union { _Float16 h; u16 u; } v; v.h = (_Float16)f; return v.u;
}

// async global->LDS, 16B per lane. LDS dest is wave-uniform base + lane*16.
__device__ __forceinline__ void async16(const void* g, void* l) {
  __builtin_amdgcn_global_load_lds(
      (const __attribute__((address_space(1))) unsigned int*)(uintptr_t)g,
      (__attribute__((address_space(3))) unsigned int*)(uint32_t)(uintptr_t)l,
      16, 0, 0);
}

// ---------------- gating: fp64-exact logits, top-2, scatter to expert lists --
__global__ __launch_bounds__(256) void gate_kernel(
    const float* __restrict__ x, const float* __restrict__ gumbel,
    const float* __restrict__ gate_w, const float* __restrict__ gate_b,
    int* __restrict__ counts, int* __restrict__ tok_list,
    int* __restrict__ tok_e, int* __restrict__ tok_p, float* __restrict__ tok_w)
{
  int t = blockIdx.x * 4 + (threadIdx.x >> 6);
  int lane = threadIdx.x & 63;
  const float* xr = x + (size_t)t * DMODEL;
  double acc[NEXP];
#pragma unroll
  for (int e = 0; e < NEXP; ++e) acc[e] = 0.0;
#pragma unroll
  for (int i = 0; i < DMODEL / 64; ++i) {
    int d = lane + i * 64;
    float xv = xr[d];
    const float4* gw = (const float4*)(gate_w + (size_t)d * NEXP);
    float4 g0 = gw[0], g1 = gw[1];
    acc[0] += (double)xv * (double)g0.x;
    acc[1] += (double)xv * (double)g0.y;
    acc[2] += (double)xv * (double)g0.z;
    acc[3] += (double)xv * (double)g0.w;
    acc[4] += (double)xv * (double)g1.x;
    acc[5] += (double)xv * (double)g1.y;
    acc[6] += (double)xv * (double)g1.z;
    acc[7] += (double)xv * (double)g1.w;
  }
#pragma unroll
  for (int e = 0; e < NEXP; ++e) {
    double v = acc[e];
    for (int off = 32; off > 0; off >>= 1) v += __shfl_down(v, off, 64);
    acc[e] = v;
  }
  if (lane == 0) {
    float noisy[NEXP];
#pragma unroll
    for (int e = 0; e < NEXP; ++e)
      noisy[e] = (float)(acc[e] + (double)gate_b[e]) + gumbel[(size_t)t * NEXP + e];
    int i0 = 0;
    for (int e = 1; e < NEXP; ++e) if (noisy[e] > noisy[i0]) i0 = e;
    int i1 = -1;
    for (int e = 0; e < NEXP; ++e) {
      if (e == i0) continue;
      if (i1 < 0 || noisy[e] > noisy[i1]) i1 = e;
    }
    float ex = expf(noisy[i1] - noisy[i0]);
    float w0 = 1.0f / (1.0f + ex);
    float w1 = ex / (1.0f + ex);
    int p0 = atomicAdd(&counts[i0], 1);
    tok_list[i0 * T_TOKENS + p0] = t;
    int p1 = atomicAdd(&counts[i1], 1);
    tok_list[i1 * T_TOKENS + p1] = t;
    tok_e[2 * t] = i0; tok_p[2 * t] = p0; tok_w[2 * t] = w0;
    tok_e[2 * t + 1] = i1; tok_p[2 * t + 1] = p1; tok_w[2 * t + 1] = w1;
  }
}

__global__ void offsets_kernel(const int* __restrict__ counts, int* __restrict__ offs) {
  if (threadIdx.x == 0 && blockIdx.x == 0) {
    int s = 0;
    for (int e = 0; e < NEXP; ++e) { offs[e] = s; s += counts[e]; }
  }
}

__global__ __launch_bounds__(256) void slots_kernel(
    const int* __restrict__ offs, const int* __restrict__ tok_e,
    const int* __restrict__ tok_p, int* __restrict__ tok_slot)
{
  int i = blockIdx.x * 256 + threadIdx.x;
  if (i < 2 * T_TOKENS) tok_slot[i] = offs[tok_e[i]] + tok_p[i];
}

// ---------------- fp32 -> fp16 conversions -----------------------------------
__global__ __launch_bounds__(256) void cvt_f16_kernel(
    const float* __restrict__ in, u16* __restrict__ out, int n4)
{
  int i = blockIdx.x * 256 + threadIdx.x;
  if (i < n4) {
    float4 v = ((const float4*)in)[i];
    uint2 o;
    o.x = (unsigned)f2h(v.x) | ((unsigned)f2h(v.y) << 16);
    o.y = (unsigned)f2h(v.z) | ((unsigned)f2h(v.w) << 16);
    ((uint2*)out)[i] = o;
  }
}

// in [rows][cols] fp32 -> out [cols][rows] fp16, per-expert (blockIdx.z)
__global__ __launch_bounds__(256) void transpose_cvt_kernel(
    const float* __restrict__ in, u16* __restrict__ out, int rows, int cols)
{
  in  += (size_t)blockIdx.z * rows * cols;
  out += (size_t)blockIdx.z * rows * cols;
  int c0 = blockIdx.x * 64, r0 = blockIdx.y * 64;
  __shared__ u16 T[64][80];   // pad: row stride 160B
  int tid = threadIdx.x;
  int tr = tid >> 4;
  int tc = (tid & 15) * 4;
#pragma unroll
  for (int i = 0; i < 4; ++i) {
    int r = tr + i * 16;
    float4 v = *(const float4*)&in[(size_t)(r0 + r) * cols + (c0 + tc)];
    T[tc + 0][r] = f2h(v.x); T[tc + 1][r] = f2h(v.y);
    T[tc + 2][r] = f2h(v.z); T[tc + 3][r] = f2h(v.w);
  }
  __syncthreads();
  int orr = tid >> 3;
  int occ = (tid & 7) * 8;
#pragma unroll
  for (int i = 0; i < 2; ++i) {
    int r = orr + i * 32;
    uint4 d = *(const uint4*)&T[r][occ];
    *(uint4*)&out[(size_t)(c0 + r) * rows + (r0 + occ)] = d;
  }
}

// =====================================================================
// Pipelined MFMA GEMMs: BK=32, quad-buffered LDS (4x16KB), prefetch
// DEPTH 3: loads for tile k+3 issued at step k, waited with raw-asm
// s_waitcnt vmcnt(12)+s_barrier. Staging is UNCONDITIONAL with index
// wraparound ((k+3) & (NK-1)) so exactly 16 loads are in flight at
// every wait and vmcnt(12) always retires precisely tile k's 4 loads.
// (A conditional tail-stage broke this invariant and raced — R1.)
// 4-chunk XOR swizzle (conflict-free at 64B row stride), XCD-clustered
// tile remap (dispatch-linear%8 == XCD heuristic).
// =====================================================================

// ---------------- GEMM1: H = relu(X[gather] @ W1 + b1), fp16 out -------------
__global__ __launch_bounds__(256, 4) void gemm1_kernel(
    const u16* __restrict__ xh, const u16* __restrict__ w1t,
    const float* __restrict__ b1,
    const int* __restrict__ counts, const int* __restrict__ offs,
    const int* __restrict__ tok_list, u16* __restrict__ H)
{
  const int e = blockIdx.z;
  const int count = counts[e];
  // XCD remap: x = XCD. Live window (bm<16): each XCD owns an 8bm x 8bn region.
  const int x = blockIdx.x & 7, q = blockIdx.x >> 3, byy = blockIdx.y;
  int bm, bn;
  if (q < 2) {
    int t = ((q & 1) << 5) | byy;        // 0..63
    bm = ((x & 1) << 3) | (t & 7);       // 0..15
    bn = ((x >> 1) << 3) | (t >> 3);     // 0..31
  } else {
    bm = (q << 3) | (byy & 7);           // 16..63
    bn = ((byy >> 3) << 3) | x;
  }
  if (bm * 128 >= count) return;
  const int off = offs[e];

  __shared__ __align__(16) u16 sm[4][2][4096];   // [buf][A/B][128*32] = 64KB

  const int tid = threadIdx.x;
  const int w = tid >> 6, lane = tid & 63;
  const int wm = w >> 1, wn = w & 1;
  const int row16 = lane & 15, quad = lane >> 4;
  const int r = lane >> 2;
  const int cg8 = (((lane & 3) ^ (r & 3)) << 3);   // swizzled k-chunk (halves)
  const int cm1 = count - 1;

  const u16* agA[2]; const u16* agB[2];
#pragma unroll
  for (int j = 0; j < 2; ++j) {
    int m = bm * 128 + w * 32 + j * 16 + r;
    int t = tok_list[e * T_TOKENS + (m < cm1 ? m : cm1)];
    agA[j] = xh + (size_t)t * DMODEL + cg8;
    int nrow = bn * 128 + w * 32 + j * 16 + r;
    agB[j] = w1t + ((size_t)e * DFF + nrow) * DMODEL + cg8;
  }
  const int ldsoff = w * 1024;
  const int cslot = ((quad ^ (row16 & 3)) << 3);

  f32x4 acc[4][4] = {};

#define STAGE1(k, b) { int ko = (k) << 5; \
    async16(agA[0] + ko, &sm[b][0][ldsoff]); \
    async16(agA[1] + ko, &sm[b][0][ldsoff + 512]); \
    async16(agB[0] + ko, &sm[b][1][ldsoff]); \
    async16(agB[1] + ko, &sm[b][1][ldsoff + 512]); }

  constexpr int NK = DMODEL / 32;   // 32
  STAGE1(0, 0); STAGE1(1, 1); STAGE1(2, 2);
  for (int k = 0; k < NK; ++k) {
    const int b = k & 3;
    STAGE1((k + 3) & (NK - 1), (k + 3) & 3);   // unconditional: keeps vmcnt exact
    // wait: tiles k+1,k+2,k+3 (12 loads) stay in flight; tile k done.
    asm volatile("s_waitcnt vmcnt(12)\n\ts_barrier" ::: "memory");
    f16x8 af[4], bf[4];
#pragma unroll
    for (int f = 0; f < 4; ++f) {
      af[f] = *(const f16x8*)&sm[b][0][(wm * 64 + f * 16 + row16) * 32 + cslot];
      bf[f] = *(const f16x8*)&sm[b][1][(wn * 64 + f * 16 + row16) * 32 + cslot];
    }
#pragma unroll
    for (int fm = 0; fm < 4; ++fm)
#pragma unroll
      for (int fn = 0; fn < 4; ++fn)
        acc[fm][fn] = __builtin_amdgcn_mfma_f32_16x16x32_f16(bf[fn], af[fm], acc[fm][fn], 0, 0, 0);
    asm volatile("s_barrier" ::: "memory");
  }

  // lane holds m = wm*64+fm*16+row16 ; n = wn*64+fn*16+quad*4+{0..3}
  const int nb = bn * 128 + wn * 64 + quad * 4;
  const float* b1e = b1 + (size_t)e * DFF + nb;
#pragma unroll
  for (int fm = 0; fm < 4; ++fm) {
    int m = bm * 128 + wm * 64 + fm * 16 + row16;
    if (m < count) {
      u16* hr = H + (size_t)(off + m) * DFF + nb;
#pragma unroll
      for (int fn = 0; fn < 4; ++fn) {
        float4 bv = *(const float4*)(b1e + fn * 16);
        union { _Float16 h[4]; uint2 u; } pk;
        float v0 = acc[fm][fn][0] + bv.x; pk.h[0] = (_Float16)(v0 > 0.f ? v0 : 0.f);
        float v1 = acc[fm][fn][1] + bv.y; pk.h[1] = (_Float16)(v1 > 0.f ? v1 : 0.f);
        float v2 = acc[fm][fn][2] + bv.z; pk.h[2] = (_Float16)(v2 > 0.f ? v2 : 0.f);
        float v3 = acc[fm][fn][3] + bv.w; pk.h[3] = (_Float16)(v3 > 0.f ? v3 : 0.f);
        *(uint2*)(hr + fn * 16) = pk.u;
      }
    }
  }
}

// ---------------- GEMM2: P[slot] = H[slot] @ W2 + b2 (fp32, coalesced) -------
__global__ __launch_bounds__(256, 4) void gemm2_kernel(
    const u16* __restrict__ H, const u16* __restrict__ w2t,
    const float* __restrict__ b2,
    const int* __restrict__ counts, const int* __restrict__ offs,
    float* __restrict__ P)
{
  const int e = blockIdx.z;
  const int count = counts[e];
  // XCD remap: live window (bm<16): each XCD owns a 4bm x 4bn region.
  const int x = blockIdx.x & 7, q = blockIdx.x >> 3, byy = blockIdx.y; // byy 0..7
  int bm, bn;
  if (q < 2) {
    int t = ((q & 1) << 3) | byy;        // 0..15
    bm = ((x & 3) << 2) | (t & 3);       // 0..15
    bn = ((x >> 2) << 2) | (t >> 2);     // 0..7
  } else {
    bm = (q << 3) | byy;                 // 16..63
    bn = x;
  }
  if (bm * 128 >= count) return;
  const int off = offs[e];

  __shared__ __align__(16) u16 sm[4][2][4096];

  const int tid = threadIdx.x;
  const int w = tid >> 6, lane = tid & 63;
  const int wm = w >> 1, wn = w & 1;
  const int row16 = lane & 15, quad = lane >> 4;
  const int r = lane >> 2;
  const int cg8 = (((lane & 3) ^ (r & 3)) << 3);
  const int cm1 = count - 1;

  const u16* agA[2]; const u16* agB[2];
#pragma unroll
  for (int j = 0; j < 2; ++j) {
    int m = bm * 128 + w * 32 + j * 16 + r;
    agA[j] = H + (size_t)(off + (m < cm1 ? m : cm1)) * DFF + cg8;
    int nrow = bn * 128 + w * 32 + j * 16 + r;
    agB[j] = w2t + ((size_t)e * DMODEL + nrow) * DFF + cg8;
  }
  const int ldsoff = w * 1024;
  const int cslot = ((quad ^ (row16 & 3)) << 3);

  f32x4 acc[4][4] = {};

  constexpr int NK = DFF / 32;   // 128
  STAGE1(0, 0); STAGE1(1, 1); STAGE1(2, 2);
  for (int k = 0; k < NK; ++k) {
    const int b = k & 3;
    STAGE1((k + 3) & (NK - 1), (k + 3) & 3);   // unconditional: keeps vmcnt exact
    asm volatile("s_waitcnt vmcnt(12)\n\ts_barrier" ::: "memory");
    f16x8 af[4], bf[4];
#pragma unroll
    for (int f = 0; f < 4; ++f) {
      af[f] = *(const f16x8*)&sm[b][0][(wm * 64 + f * 16 + row16) * 32 + cslot];
      bf[f] = *(const f16x8*)&sm[b][1][(wn * 64 + f * 16 + row16) * 32 + cslot];
    }
#pragma unroll
    for (int fm = 0; fm < 4; ++fm)
#pragma unroll
      for (int fn = 0; fn < 4; ++fn)
        acc[fm][fn] = __builtin_amdgcn_mfma_f32_16x16x32_f16(bf[fn], af[fm], acc[fm][fn], 0, 0, 0);
    asm volatile("s_barrier" ::: "memory");
  }

  const int nb = bn * 128 + wn * 64 + quad * 4;
  const float* b2e = b2 + (size_t)e * DMODEL + nb;
#pragma unroll
  for (int fm = 0; fm < 4; ++fm) {
    int m = bm * 128 + wm * 64 + fm * 16 + row16;
    if (m < count) {
      float* pr = P + (size_t)(off + m) * DMODEL + nb;
#pragma unroll
      for (int fn = 0; fn < 4; ++fn) {
        float4 bv = *(const float4*)(b2e + fn * 16);
        float4 o;
        o.x = acc[fm][fn][0] + bv.x;
        o.y = acc[fm][fn][1] + bv.y;
        o.z = acc[fm][fn][2] + bv.z;
        o.w = acc[fm][fn][3] + bv.w;
        *(float4*)(pr + fn * 16) = o;
      }
    }
  }
}

// ---------------- combine: out[t] = w0*P[s0] + w1*P[s1] ----------------------
__global__ __launch_bounds__(256) void combine_kernel(
    const float* __restrict__ P, const int* __restrict__ tok_slot,
    const float* __restrict__ tok_w, float* __restrict__ out)
{
  int idx = blockIdx.x * 256 + threadIdx.x;
  int t = idx >> 8;
  int d = (idx & 255) << 2;
  int s0 = tok_slot[2 * t], s1 = tok_slot[2 * t + 1];
  float w0 = tok_w[2 * t], w1 = tok_w[2 * t + 1];
  float4 a = *(const float4*)(P + (size_t)s0 * DMODEL + d);
  float4 b = *(const float4*)(P + (size_t)s1 * DMODEL + d);
  float4 o;
  o.x = w0 * a.x + w1 * b.x;
  o.y = w0 * a.y + w1 * b.y;
  o.z = w0 * a.z + w1 * b.z;
  o.w = w0 * a.w + w1 * b.w;
  *(float4*)(out + (size_t)t * DMODEL + d) = o;
}

// ---------------- launch -----------------------------------------------------
extern "C" void kernel_launch(void* const* d_in, const int* in_sizes, int n_in,
                              void* d_out, int out_size, void* d_ws, size_t ws_size,
                              hipStream_t stream)
{
  const float* x      = (const float*)d_in[0];
  const float* gumbel = (const float*)d_in[1];
  const float* gate_w = (const float*)d_in[2];
  const float* gate_b = (const float*)d_in[3];
  const float* w1     = (const float*)d_in[4];
  const float* b1     = (const float*)d_in[5];
  const float* w2     = (const float*)d_in[6];
  const float* b2     = (const float*)d_in[7];
  float* out = (float*)d_out;
  char* ws = (char*)d_ws;

  // workspace layout (~286 MB; P overlays dead w1t region)
  constexpr size_t OFF_COUNTS = 0;
  constexpr size_t OFF_OFFS   = 64;
  constexpr size_t OFF_TOK    = 4096;
  constexpr size_t OFF_TE     = OFF_TOK + (size_t)NEXP * T_TOKENS * 4;
  constexpr size_t OFF_TP     = OFF_TE + 2 * T_TOKENS * 4;
  constexpr size_t OFF_TW     = OFF_TP + 2 * T_TOKENS * 4;
  constexpr size_t OFF_TS     = OFF_TW + 2 * T_TOKENS * 4;
  constexpr size_t OFF_XH     = OFF_TS + 2 * T_TOKENS * 4;
  constexpr size_t OFF_W1T    = OFF_XH  + (size_t)T_TOKENS * DMODEL * 2;
  constexpr size_t OFF_W2T    = OFF_W1T + (size_t)NEXP * DFF * DMODEL * 2;
  constexpr size_t OFF_H      = OFF_W2T + (size_t)NEXP * DMODEL * DFF * 2;
  constexpr size_t OFF_P      = OFF_W1T;  // w1t dead after gemm1

  int*   counts = (int*)(ws + OFF_COUNTS);
  int*   offs   = (int*)(ws + OFF_OFFS);
  int*   tokl   = (int*)(ws + OFF_TOK);
  int*   tok_e  = (int*)(ws + OFF_TE);
  int*   tok_p  = (int*)(ws + OFF_TP);
  float* tok_w  = (float*)(ws + OFF_TW);
  int*   tok_s  = (int*)(ws + OFF_TS);
  u16*   xh     = (u16*)(ws + OFF_XH);
  u16*   w1t    = (u16*)(ws + OFF_W1T);
  u16*   w2t    = (u16*)(ws + OFF_W2T);
  u16*   H      = (u16*)(ws + OFF_H);
  float* P      = (float*)(ws + OFF_P);

  hipMemsetAsync(ws + OFF_COUNTS, 0, 1024, stream);

  cvt_f16_kernel<<<(T_TOKENS * DMODEL / 4 + 255) / 256, 256, 0, stream>>>(
      x, xh, T_TOKENS * DMODEL / 4);
  transpose_cvt_kernel<<<dim3(DFF / 64, DMODEL / 64, NEXP), 256, 0, stream>>>(
      w1, w1t, DMODEL, DFF);
  transpose_cvt_kernel<<<dim3(DMODEL / 64, DFF / 64, NEXP), 256, 0, stream>>>(
      w2, w2t, DFF, DMODEL);
  gate_kernel<<<T_TOKENS / 4, 256, 0, stream>>>(
      x, gumbel, gate_w, gate_b, counts, tokl, tok_e, tok_p, tok_w);
  offsets_kernel<<<1, 64, 0, stream>>>(counts, offs);
  slots_kernel<<<(2 * T_TOKENS + 255) / 256, 256, 0, stream>>>(
      offs, tok_e, tok_p, tok_s);
  gemm1_kernel<<<dim3(64, 32, NEXP), 256, 0, stream>>>(
      xh, w1t, b1, counts, offs, tokl, H);
  gemm2_kernel<<<dim3(64, 8, NEXP), 256, 0, stream>>>(
      H, w2t, b2, counts, offs, P);
  combine_kernel<<<T_TOKENS, 256, 0, stream>>>(P, tok_s, tok_w, out);
}

// Round 3
// 990.645 us; speedup vs baseline: 1.2224x; 1.2186x over previous
//
#include <hip/hip_runtime.h>
#include <cstdint>

#define T_TOKENS 8192
#define DMODEL 1024
#define DFF 4096
#define NEXP 8

typedef _Float16 f16x8 __attribute__((ext_vector_type(8)));
typedef float f32x4 __attribute__((ext_vector_type(4)));
using u16 = unsigned short;

__device__ __forceinline__ u16 f2h(float f) {
  union { _Float16 h; u16 u; } v; v.h = (_Float16)f; return v.u;
}

// async global->LDS, 16B per lane. LDS dest is wave-uniform base + lane*16.
__device__ __forceinline__ void async16(const void* g, void* l) {
  __builtin_amdgcn_global_load_lds(
      (const __attribute__((address_space(1))) unsigned int*)(uintptr_t)g,
      (__attribute__((address_space(3))) unsigned int*)(uint32_t)(uintptr_t)l,
      16, 0, 0);
}

// ---------------- gating: fp64-exact logits, top-2, scatter to expert lists --
__global__ __launch_bounds__(256) void gate_kernel(
    const float* __restrict__ x, const float* __restrict__ gumbel,
    const float* __restrict__ gate_w, const float* __restrict__ gate_b,
    int* __restrict__ counts, int* __restrict__ tok_list,
    int* __restrict__ tok_e, int* __restrict__ tok_p, float* __restrict__ tok_w)
{
  int t = blockIdx.x * 4 + (threadIdx.x >> 6);
  int lane = threadIdx.x & 63;
  const float* xr = x + (size_t)t * DMODEL;
  double acc[NEXP];
#pragma unroll
  for (int e = 0; e < NEXP; ++e) acc[e] = 0.0;
#pragma unroll
  for (int i = 0; i < DMODEL / 64; ++i) {
    int d = lane + i * 64;
    float xv = xr[d];
    const float4* gw = (const float4*)(gate_w + (size_t)d * NEXP);
    float4 g0 = gw[0], g1 = gw[1];
    acc[0] += (double)xv * (double)g0.x;
    acc[1] += (double)xv * (double)g0.y;
    acc[2] += (double)xv * (double)g0.z;
    acc[3] += (double)xv * (double)g0.w;
    acc[4] += (double)xv * (double)g1.x;
    acc[5] += (double)xv * (double)g1.y;
    acc[6] += (double)xv * (double)g1.z;
    acc[7] += (double)xv * (double)g1.w;
  }
#pragma unroll
  for (int e = 0; e < NEXP; ++e) {
    double v = acc[e];
    for (int off = 32; off > 0; off >>= 1) v += __shfl_down(v, off, 64);
    acc[e] = v;
  }
  if (lane == 0) {
    float noisy[NEXP];
#pragma unroll
    for (int e = 0; e < NEXP; ++e)
      noisy[e] = (float)(acc[e] + (double)gate_b[e]) + gumbel[(size_t)t * NEXP + e];
    int i0 = 0;
    for (int e = 1; e < NEXP; ++e) if (noisy[e] > noisy[i0]) i0 = e;
    int i1 = -1;
    for (int e = 0; e < NEXP; ++e) {
      if (e == i0) continue;
      if (i1 < 0 || noisy[e] > noisy[i1]) i1 = e;
    }
    float ex = expf(noisy[i1] - noisy[i0]);
    float w0 = 1.0f / (1.0f + ex);
    float w1 = ex / (1.0f + ex);
    int p0 = atomicAdd(&counts[i0], 1);
    tok_list[i0 * T_TOKENS + p0] = t;
    int p1 = atomicAdd(&counts[i1], 1);
    tok_list[i1 * T_TOKENS + p1] = t;
    tok_e[2 * t] = i0; tok_p[2 * t] = p0; tok_w[2 * t] = w0;
    tok_e[2 * t + 1] = i1; tok_p[2 * t + 1] = p1; tok_w[2 * t + 1] = w1;
  }
}

__global__ void offsets_kernel(const int* __restrict__ counts, int* __restrict__ offs) {
  if (threadIdx.x == 0 && blockIdx.x == 0) {
    int s = 0;
    for (int e = 0; e < NEXP; ++e) { offs[e] = s; s += counts[e]; }
  }
}

__global__ __launch_bounds__(256) void slots_kernel(
    const int* __restrict__ offs, const int* __restrict__ tok_e,
    const int* __restrict__ tok_p, int* __restrict__ tok_slot)
{
  int i = blockIdx.x * 256 + threadIdx.x;
  if (i < 2 * T_TOKENS) tok_slot[i] = offs[tok_e[i]] + tok_p[i];
}

// ---------------- fp32 -> fp16 conversions -----------------------------------
__global__ __launch_bounds__(256) void cvt_f16_kernel(
    const float* __restrict__ in, u16* __restrict__ out, int n4)
{
  int i = blockIdx.x * 256 + threadIdx.x;
  if (i < n4) {
    float4 v = ((const float4*)in)[i];
    uint2 o;
    o.x = (unsigned)f2h(v.x) | ((unsigned)f2h(v.y) << 16);
    o.y = (unsigned)f2h(v.z) | ((unsigned)f2h(v.w) << 16);
    ((uint2*)out)[i] = o;
  }
}

// in [rows][cols] fp32 -> out [cols][rows] fp16, per-expert (blockIdx.z)
__global__ __launch_bounds__(256) void transpose_cvt_kernel(
    const float* __restrict__ in, u16* __restrict__ out, int rows, int cols)
{
  in  += (size_t)blockIdx.z * rows * cols;
  out += (size_t)blockIdx.z * rows * cols;
  int c0 = blockIdx.x * 64, r0 = blockIdx.y * 64;
  __shared__ u16 T[64][80];   // pad: row stride 160B
  int tid = threadIdx.x;
  int tr = tid >> 4;
  int tc = (tid & 15) * 4;
#pragma unroll
  for (int i = 0; i < 4; ++i) {
    int r = tr + i * 16;
    float4 v = *(const float4*)&in[(size_t)(r0 + r) * cols + (c0 + tc)];
    T[tc + 0][r] = f2h(v.x); T[tc + 1][r] = f2h(v.y);
    T[tc + 2][r] = f2h(v.z); T[tc + 3][r] = f2h(v.w);
  }
  __syncthreads();
  int orr = tid >> 3;
  int occ = (tid & 7) * 8;
#pragma unroll
  for (int i = 0; i < 2; ++i) {
    int r = orr + i * 32;
    uint4 d = *(const uint4*)&T[r][occ];
    *(uint4*)&out[(size_t)(c0 + r) * rows + (r0 + occ)] = d;
  }
}

// =====================================================================
// 256x256 MFMA GEMMs: BK=32, 8 waves (2x4), 128x64 out/wave, 64KB LDS
// double-buffer. Pipeline skeleton identical to the verified 128-tile
// version: unconditional wrapped STAGE (4 async16/thread), raw-asm
// s_waitcnt vmcnt(4)+s_barrier (next tile's 4 loads stay in flight),
// 4-chunk XOR swizzle (source+read involution). Bigger tile doubles
// MFMA:LDS-read ratio (32:12 vs 16:8) and K-step length (~2x cover of
// HBM latency at depth-1), at same waves/CU (8).
// =====================================================================

// ---------------- GEMM1: H = relu(X[gather] @ W1 + b1), fp16 out -------------
__global__ __launch_bounds__(512, 2) void gemm1_kernel(
    const u16* __restrict__ xh, const u16* __restrict__ w1t,
    const float* __restrict__ b1,
    const int* __restrict__ counts, const int* __restrict__ offs,
    const int* __restrict__ tok_list, u16* __restrict__ H)
{
  const int e = blockIdx.z;
  const int count = counts[e];
  // XCD heuristic: dispatch-linear%8 == x&7 (y,z strides are mult of 8).
  // bn from x so each XCD keeps 2 W1 n-panels (2x512KB) L2-resident.
  const int bxx = blockIdx.x;                       // 0..15
  const int bn = ((bxx & 7) << 1) | (bxx >> 3);     // bijective 0..15
  const int bm = blockIdx.y;                        // 0..31
  if (bm * 256 >= count) return;
  const int off = offs[e];

  __shared__ __align__(16) u16 sm[2][2][8192];   // [buf][A/B][256*32] = 64KB

  const int tid = threadIdx.x;
  const int w = tid >> 6, lane = tid & 63;
  const int wm = w >> 2, wn = w & 3;               // wave grid 2(M) x 4(N)
  const int row16 = lane & 15, quad = lane >> 4;
  const int r = lane >> 2;
  const int cg8 = (((lane & 3) ^ (r & 3)) << 3);   // swizzled k-chunk (halves)
  const int cm1 = count - 1;

  const u16* agA[2]; const u16* agB[2];
#pragma unroll
  for (int j = 0; j < 2; ++j) {
    int m = bm * 256 + w * 32 + j * 16 + r;        // 8 waves x 32 rows = 256
    int t = tok_list[e * T_TOKENS + (m < cm1 ? m : cm1)];
    agA[j] = xh + (size_t)t * DMODEL + cg8;
    int nrow = bn * 256 + w * 32 + j * 16 + r;
    agB[j] = w1t + ((size_t)e * DFF + nrow) * DMODEL + cg8;
  }
  const int ldsoff = w * 1024;                     // 32 rows * 32 cols per wave
  const int cslot = ((quad ^ (row16 & 3)) << 3);

  f32x4 acc[8][4] = {};

#define STAGE1(k, b) { int ko = (k) << 5; \
    async16(agA[0] + ko, &sm[b][0][ldsoff]); \
    async16(agA[1] + ko, &sm[b][0][ldsoff + 512]); \
    async16(agB[0] + ko, &sm[b][1][ldsoff]); \
    async16(agB[1] + ko, &sm[b][1][ldsoff + 512]); }

  constexpr int NK = DMODEL / 32;   // 32
  STAGE1(0, 0);
  for (int k = 0; k < NK; ++k) {
    const int b = k & 1;
    STAGE1((k + 1) & (NK - 1), b ^ 1);   // unconditional: keeps vmcnt exact
    asm volatile("s_waitcnt vmcnt(4)\n\ts_barrier" ::: "memory");
    f16x8 af[8], bf[4];
#pragma unroll
    for (int f = 0; f < 8; ++f)
      af[f] = *(const f16x8*)&sm[b][0][(wm * 128 + f * 16 + row16) * 32 + cslot];
#pragma unroll
    for (int f = 0; f < 4; ++f)
      bf[f] = *(const f16x8*)&sm[b][1][(wn * 64 + f * 16 + row16) * 32 + cslot];
#pragma unroll
    for (int fm = 0; fm < 8; ++fm)
#pragma unroll
      for (int fn = 0; fn < 4; ++fn)
        acc[fm][fn] = __builtin_amdgcn_mfma_f32_16x16x32_f16(bf[fn], af[fm], acc[fm][fn], 0, 0, 0);
    asm volatile("s_barrier" ::: "memory");
  }

  // lane holds m = wm*128+fm*16+row16 ; n = wn*64+fn*16+quad*4+{0..3}
  const int nb = bn * 256 + wn * 64 + quad * 4;
  const float* b1e = b1 + (size_t)e * DFF + nb;
#pragma unroll
  for (int fm = 0; fm < 8; ++fm) {
    int m = bm * 256 + wm * 128 + fm * 16 + row16;
    if (m < count) {
      u16* hr = H + (size_t)(off + m) * DFF + nb;
#pragma unroll
      for (int fn = 0; fn < 4; ++fn) {
        float4 bv = *(const float4*)(b1e + fn * 16);
        union { _Float16 h[4]; uint2 u; } pk;
        float v0 = acc[fm][fn][0] + bv.x; pk.h[0] = (_Float16)(v0 > 0.f ? v0 : 0.f);
        float v1 = acc[fm][fn][1] + bv.y; pk.h[1] = (_Float16)(v1 > 0.f ? v1 : 0.f);
        float v2 = acc[fm][fn][2] + bv.z; pk.h[2] = (_Float16)(v2 > 0.f ? v2 : 0.f);
        float v3 = acc[fm][fn][3] + bv.w; pk.h[3] = (_Float16)(v3 > 0.f ? v3 : 0.f);
        *(uint2*)(hr + fn * 16) = pk.u;
      }
    }
  }
}

// ---------------- GEMM2: P[slot] = H[slot] @ W2 + b2 (fp32, coalesced) -------
__global__ __launch_bounds__(512, 2) void gemm2_kernel(
    const u16* __restrict__ H, const u16* __restrict__ w2t,
    const float* __restrict__ b2,
    const int* __restrict__ counts, const int* __restrict__ offs,
    float* __restrict__ P)
{
  const int e = blockIdx.z;
  const int count = counts[e];
  // grid (4,32,8): XCD = (x+4y)%8 -> each XCD sees a single bn (=x'%4):
  // one 2MB W2 n-panel resident per XCD L2. No remap needed.
  const int bn = blockIdx.x;                        // 0..3
  const int bm = blockIdx.y;                        // 0..31
  if (bm * 256 >= count) return;
  const int off = offs[e];

  __shared__ __align__(16) u16 sm[2][2][8192];

  const int tid = threadIdx.x;
  const int w = tid >> 6, lane = tid & 63;
  const int wm = w >> 2, wn = w & 3;
  const int row16 = lane & 15, quad = lane >> 4;
  const int r = lane >> 2;
  const int cg8 = (((lane & 3) ^ (r & 3)) << 3);
  const int cm1 = count - 1;

  const u16* agA[2]; const u16* agB[2];
#pragma unroll
  for (int j = 0; j < 2; ++j) {
    int m = bm * 256 + w * 32 + j * 16 + r;
    agA[j] = H + (size_t)(off + (m < cm1 ? m : cm1)) * DFF + cg8;
    int nrow = bn * 256 + w * 32 + j * 16 + r;
    agB[j] = w2t + ((size_t)e * DMODEL + nrow) * DFF + cg8;
  }
  const int ldsoff = w * 1024;
  const int cslot = ((quad ^ (row16 & 3)) << 3);

  f32x4 acc[8][4] = {};

  constexpr int NK = DFF / 32;   // 128
  STAGE1(0, 0);
  for (int k = 0; k < NK; ++k) {
    const int b = k & 1;
    STAGE1((k + 1) & (NK - 1), b ^ 1);   // unconditional: keeps vmcnt exact
    asm volatile("s_waitcnt vmcnt(4)\n\ts_barrier" ::: "memory");
    f16x8 af[8], bf[4];
#pragma unroll
    for (int f = 0; f < 8; ++f)
      af[f] = *(const f16x8*)&sm[b][0][(wm * 128 + f * 16 + row16) * 32 + cslot];
#pragma unroll
    for (int f = 0; f < 4; ++f)
      bf[f] = *(const f16x8*)&sm[b][1][(wn * 64 + f * 16 + row16) * 32 + cslot];
#pragma unroll
    for (int fm = 0; fm < 8; ++fm)
#pragma unroll
      for (int fn = 0; fn < 4; ++fn)
        acc[fm][fn] = __builtin_amdgcn_mfma_f32_16x16x32_f16(bf[fn], af[fm], acc[fm][fn], 0, 0, 0);
    asm volatile("s_barrier" ::: "memory");
  }

  const int nb = bn * 256 + wn * 64 + quad * 4;
  const float* b2e = b2 + (size_t)e * DMODEL + nb;
#pragma unroll
  for (int fm = 0; fm < 8; ++fm) {
    int m = bm * 256 + wm * 128 + fm * 16 + row16;
    if (m < count) {
      float* pr = P + (size_t)(off + m) * DMODEL + nb;
#pragma unroll
      for (int fn = 0; fn < 4; ++fn) {
        float4 bv = *(const float4*)(b2e + fn * 16);
        float4 o;
        o.x = acc[fm][fn][0] + bv.x;
        o.y = acc[fm][fn][1] + bv.y;
        o.z = acc[fm][fn][2] + bv.z;
        o.w = acc[fm][fn][3] + bv.w;
        *(float4*)(pr + fn * 16) = o;
      }
    }
  }
}

// ---------------- combine: out[t] = w0*P[s0] + w1*P[s1] ----------------------
__global__ __launch_bounds__(256) void combine_kernel(
    const float* __restrict__ P, const int* __restrict__ tok_slot,
    const float* __restrict__ tok_w, float* __restrict__ out)
{
  int idx = blockIdx.x * 256 + threadIdx.x;
  int t = idx >> 8;
  int d = (idx & 255) << 2;
  int s0 = tok_slot[2 * t], s1 = tok_slot[2 * t + 1];
  float w0 = tok_w[2 * t], w1 = tok_w[2 * t + 1];
  float4 a = *(const float4*)(P + (size_t)s0 * DMODEL + d);
  float4 b = *(const float4*)(P + (size_t)s1 * DMODEL + d);
  float4 o;
  o.x = w0 * a.x + w1 * b.x;
  o.y = w0 * a.y + w1 * b.y;
  o.z = w0 * a.z + w1 * b.z;
  o.w = w0 * a.w + w1 * b.w;
  *(float4*)(out + (size_t)t * DMODEL + d) = o;
}

// ---------------- launch -----------------------------------------------------
extern "C" void kernel_launch(void* const* d_in, const int* in_sizes, int n_in,
                              void* d_out, int out_size, void* d_ws, size_t ws_size,
                              hipStream_t stream)
{
  const float* x      = (const float*)d_in[0];
  const float* gumbel = (const float*)d_in[1];
  const float* gate_w = (const float*)d_in[2];
  const float* gate_b = (const float*)d_in[3];
  const float* w1     = (const float*)d_in[4];
  const float* b1     = (const float*)d_in[5];
  const float* w2     = (const float*)d_in[6];
  const float* b2     = (const float*)d_in[7];
  float* out = (float*)d_out;
  char* ws = (char*)d_ws;

  // workspace layout (~286 MB; P overlays dead w1t region)
  constexpr size_t OFF_COUNTS = 0;
  constexpr size_t OFF_OFFS   = 64;
  constexpr size_t OFF_TOK    = 4096;
  constexpr size_t OFF_TE     = OFF_TOK + (size_t)NEXP * T_TOKENS * 4;
  constexpr size_t OFF_TP     = OFF_TE + 2 * T_TOKENS * 4;
  constexpr size_t OFF_TW     = OFF_TP + 2 * T_TOKENS * 4;
  constexpr size_t OFF_TS     = OFF_TW + 2 * T_TOKENS * 4;
  constexpr size_t OFF_XH     = OFF_TS + 2 * T_TOKENS * 4;
  constexpr size_t OFF_W1T    = OFF_XH  + (size_t)T_TOKENS * DMODEL * 2;
  constexpr size_t OFF_W2T    = OFF_W1T + (size_t)NEXP * DFF * DMODEL * 2;
  constexpr size_t OFF_H      = OFF_W2T + (size_t)NEXP * DMODEL * DFF * 2;
  constexpr size_t OFF_P      = OFF_W1T;  // w1t dead after gemm1

  int*   counts = (int*)(ws + OFF_COUNTS);
  int*   offs   = (int*)(ws + OFF_OFFS);
  int*   tokl   = (int*)(ws + OFF_TOK);
  int*   tok_e  = (int*)(ws + OFF_TE);
  int*   tok_p  = (int*)(ws + OFF_TP);
  float* tok_w  = (float*)(ws + OFF_TW);
  int*   tok_s  = (int*)(ws + OFF_TS);
  u16*   xh     = (u16*)(ws + OFF_XH);
  u16*   w1t    = (u16*)(ws + OFF_W1T);
  u16*   w2t    = (u16*)(ws + OFF_W2T);
  u16*   H      = (u16*)(ws + OFF_H);
  float* P      = (float*)(ws + OFF_P);

  hipMemsetAsync(ws + OFF_COUNTS, 0, 1024, stream);

  cvt_f16_kernel<<<(T_TOKENS * DMODEL / 4 + 255) / 256, 256, 0, stream>>>(
      x, xh, T_TOKENS * DMODEL / 4);
  transpose_cvt_kernel<<<dim3(DFF / 64, DMODEL / 64, NEXP), 256, 0, stream>>>(
      w1, w1t, DMODEL, DFF);
  transpose_cvt_kernel<<<dim3(DMODEL / 64, DFF / 64, NEXP), 256, 0, stream>>>(
      w2, w2t, DFF, DMODEL);
  gate_kernel<<<T_TOKENS / 4, 256, 0, stream>>>(
      x, gumbel, gate_w, gate_b, counts, tokl, tok_e, tok_p, tok_w);
  offsets_kernel<<<1, 64, 0, stream>>>(counts, offs);
  slots_kernel<<<(2 * T_TOKENS + 255) / 256, 256, 0, stream>>>(
      offs, tok_e, tok_p, tok_s);
  gemm1_kernel<<<dim3(16, 32, NEXP), 512, 0, stream>>>(
      xh, w1t, b1, counts, offs, tokl, H);
  gemm2_kernel<<<dim3(4, 32, NEXP), 512, 0, stream>>>(
      H, w2t, b2, counts, offs, P);
  combine_kernel<<<T_TOKENS, 256, 0, stream>>>(P, tok_s, tok_w, out);
}

// Round 4
// 987.863 us; speedup vs baseline: 1.2258x; 1.0028x over previous
//
#include <hip/hip_runtime.h>
#include <cstdint>

#define T_TOKENS 8192
#define DMODEL 1024
#define DFF 4096
#define NEXP 8

typedef _Float16 f16x8 __attribute__((ext_vector_type(8)));
typedef float f32x4 __attribute__((ext_vector_type(4)));
using u16 = unsigned short;

__device__ __forceinline__ u16 f2h(float f) {
  union { _Float16 h; u16 u; } v; v.h = (_Float16)f; return v.u;
}

// async global->LDS, 16B per lane. LDS dest is wave-uniform base + lane*16.
__device__ __forceinline__ void async16(const void* g, void* l) {
  __builtin_amdgcn_global_load_lds(
      (const __attribute__((address_space(1))) unsigned int*)(uintptr_t)g,
      (__attribute__((address_space(3))) unsigned int*)(uint32_t)(uintptr_t)l,
      16, 0, 0);
}

// ---------------- gating: fp64-exact logits, top-2, scatter to expert lists --
__global__ __launch_bounds__(256) void gate_kernel(
    const float* __restrict__ x, const float* __restrict__ gumbel,
    const float* __restrict__ gate_w, const float* __restrict__ gate_b,
    int* __restrict__ counts, int* __restrict__ tok_list,
    int* __restrict__ tok_e, int* __restrict__ tok_p, float* __restrict__ tok_w)
{
  int t = blockIdx.x * 4 + (threadIdx.x >> 6);
  int lane = threadIdx.x & 63;
  const float* xr = x + (size_t)t * DMODEL;
  double acc[NEXP];
#pragma unroll
  for (int e = 0; e < NEXP; ++e) acc[e] = 0.0;
#pragma unroll
  for (int i = 0; i < DMODEL / 64; ++i) {
    int d = lane + i * 64;
    float xv = xr[d];
    const float4* gw = (const float4*)(gate_w + (size_t)d * NEXP);
    float4 g0 = gw[0], g1 = gw[1];
    acc[0] += (double)xv * (double)g0.x;
    acc[1] += (double)xv * (double)g0.y;
    acc[2] += (double)xv * (double)g0.z;
    acc[3] += (double)xv * (double)g0.w;
    acc[4] += (double)xv * (double)g1.x;
    acc[5] += (double)xv * (double)g1.y;
    acc[6] += (double)xv * (double)g1.z;
    acc[7] += (double)xv * (double)g1.w;
  }
#pragma unroll
  for (int e = 0; e < NEXP; ++e) {
    double v = acc[e];
    for (int off = 32; off > 0; off >>= 1) v += __shfl_down(v, off, 64);
    acc[e] = v;
  }
  if (lane == 0) {
    float noisy[NEXP];
#pragma unroll
    for (int e = 0; e < NEXP; ++e)
      noisy[e] = (float)(acc[e] + (double)gate_b[e]) + gumbel[(size_t)t * NEXP + e];
    int i0 = 0;
    for (int e = 1; e < NEXP; ++e) if (noisy[e] > noisy[i0]) i0 = e;
    int i1 = -1;
    for (int e = 0; e < NEXP; ++e) {
      if (e == i0) continue;
      if (i1 < 0 || noisy[e] > noisy[i1]) i1 = e;
    }
    float ex = expf(noisy[i1] - noisy[i0]);
    float w0 = 1.0f / (1.0f + ex);
    float w1 = ex / (1.0f + ex);
    int p0 = atomicAdd(&counts[i0], 1);
    tok_list[i0 * T_TOKENS + p0] = t;
    int p1 = atomicAdd(&counts[i1], 1);
    tok_list[i1 * T_TOKENS + p1] = t;
    tok_e[2 * t] = i0; tok_p[2 * t] = p0; tok_w[2 * t] = w0;
    tok_e[2 * t + 1] = i1; tok_p[2 * t + 1] = p1; tok_w[2 * t + 1] = w1;
  }
}

__global__ void offsets_kernel(const int* __restrict__ counts, int* __restrict__ offs) {
  if (threadIdx.x == 0 && blockIdx.x == 0) {
    int s = 0;
    for (int e = 0; e < NEXP; ++e) { offs[e] = s; s += counts[e]; }
  }
}

__global__ __launch_bounds__(256) void slots_kernel(
    const int* __restrict__ offs, const int* __restrict__ tok_e,
    const int* __restrict__ tok_p, int* __restrict__ tok_slot)
{
  int i = blockIdx.x * 256 + threadIdx.x;
  if (i < 2 * T_TOKENS) tok_slot[i] = offs[tok_e[i]] + tok_p[i];
}

// ---------------- fp32 -> fp16 conversions -----------------------------------
__global__ __launch_bounds__(256) void cvt_f16_kernel(
    const float* __restrict__ in, u16* __restrict__ out, int n4)
{
  int i = blockIdx.x * 256 + threadIdx.x;
  if (i < n4) {
    float4 v = ((const float4*)in)[i];
    uint2 o;
    o.x = (unsigned)f2h(v.x) | ((unsigned)f2h(v.y) << 16);
    o.y = (unsigned)f2h(v.z) | ((unsigned)f2h(v.w) << 16);
    ((uint2*)out)[i] = o;
  }
}

// in [rows][cols] fp32 -> out [cols][rows] fp16, per-expert (blockIdx.z)
__global__ __launch_bounds__(256) void transpose_cvt_kernel(
    const float* __restrict__ in, u16* __restrict__ out, int rows, int cols)
{
  in  += (size_t)blockIdx.z * rows * cols;
  out += (size_t)blockIdx.z * rows * cols;
  int c0 = blockIdx.x * 64, r0 = blockIdx.y * 64;
  __shared__ u16 T[64][80];   // pad: row stride 160B
  int tid = threadIdx.x;
  int tr = tid >> 4;
  int tc = (tid & 15) * 4;
#pragma unroll
  for (int i = 0; i < 4; ++i) {
    int r = tr + i * 16;
    float4 v = *(const float4*)&in[(size_t)(r0 + r) * cols + (c0 + tc)];
    T[tc + 0][r] = f2h(v.x); T[tc + 1][r] = f2h(v.y);
    T[tc + 2][r] = f2h(v.z); T[tc + 3][r] = f2h(v.w);
  }
  __syncthreads();
  int orr = tid >> 3;
  int occ = (tid & 7) * 8;
#pragma unroll
  for (int i = 0; i < 2; ++i) {
    int r = orr + i * 32;
    uint4 d = *(const uint4*)&T[r][occ];
    *(uint4*)&out[(size_t)(c0 + r) * rows + (r0 + occ)] = d;
  }
}

// =====================================================================
// 256x256 MFMA GEMMs: BK=32, 8 waves (2x4), 128x64 out/wave.
// gemm1: 64KB double-buffer, depth-1 (2 blocks/CU co-resident -> inter-
//        block overlap hides the per-step drain; 1024 live blocks).
// gemm2: 128KB quad-buffer, depth-3 prefetch, vmcnt(12) (only 256 live
//        blocks = 1/CU -> no inter-block overlap; deep per-wave pipeline
//        instead. LDS 64->128KB costs nothing: residency already 1).
// Both: unconditional wrapped STAGE (4 async16/thread) keeps the
// outstanding-load count exact at every wait (R1 lesson); 4-chunk XOR
// swizzle (source+read involution); raw-asm s_waitcnt+s_barrier.
// =====================================================================

// ---------------- GEMM1: H = relu(X[gather] @ W1 + b1), fp16 out -------------
__global__ __launch_bounds__(512, 2) void gemm1_kernel(
    const u16* __restrict__ xh, const u16* __restrict__ w1t,
    const float* __restrict__ b1,
    const int* __restrict__ counts, const int* __restrict__ offs,
    const int* __restrict__ tok_list, u16* __restrict__ H)
{
  const int e = blockIdx.z;
  const int count = counts[e];
  // XCD heuristic: dispatch-linear%8 == x&7 (y,z strides are mult of 8).
  // bn from x so each XCD keeps 2 W1 n-panels (2x512KB) L2-resident.
  const int bxx = blockIdx.x;                       // 0..15
  const int bn = ((bxx & 7) << 1) | (bxx >> 3);     // bijective 0..15
  const int bm = blockIdx.y;                        // 0..31
  if (bm * 256 >= count) return;
  const int off = offs[e];

  __shared__ __align__(16) u16 sm[2][2][8192];   // [buf][A/B][256*32] = 64KB

  const int tid = threadIdx.x;
  const int w = tid >> 6, lane = tid & 63;
  const int wm = w >> 2, wn = w & 3;               // wave grid 2(M) x 4(N)
  const int row16 = lane & 15, quad = lane >> 4;
  const int r = lane >> 2;
  const int cg8 = (((lane & 3) ^ (r & 3)) << 3);   // swizzled k-chunk (halves)
  const int cm1 = count - 1;

  const u16* agA[2]; const u16* agB[2];
#pragma unroll
  for (int j = 0; j < 2; ++j) {
    int m = bm * 256 + w * 32 + j * 16 + r;        // 8 waves x 32 rows = 256
    int t = tok_list[e * T_TOKENS + (m < cm1 ? m : cm1)];
    agA[j] = xh + (size_t)t * DMODEL + cg8;
    int nrow = bn * 256 + w * 32 + j * 16 + r;
    agB[j] = w1t + ((size_t)e * DFF + nrow) * DMODEL + cg8;
  }
  const int ldsoff = w * 1024;                     // 32 rows * 32 cols per wave
  const int cslot = ((quad ^ (row16 & 3)) << 3);

  f32x4 acc[8][4] = {};

#define STAGE1(k, b) { int ko = (k) << 5; \
    async16(agA[0] + ko, &sm[b][0][ldsoff]); \
    async16(agA[1] + ko, &sm[b][0][ldsoff + 512]); \
    async16(agB[0] + ko, &sm[b][1][ldsoff]); \
    async16(agB[1] + ko, &sm[b][1][ldsoff + 512]); }

  constexpr int NK = DMODEL / 32;   // 32
  STAGE1(0, 0);
  for (int k = 0; k < NK; ++k) {
    const int b = k & 1;
    STAGE1((k + 1) & (NK - 1), b ^ 1);   // unconditional: keeps vmcnt exact
    asm volatile("s_waitcnt vmcnt(4)\n\ts_barrier" ::: "memory");
    f16x8 af[8], bf[4];
#pragma unroll
    for (int f = 0; f < 8; ++f)
      af[f] = *(const f16x8*)&sm[b][0][(wm * 128 + f * 16 + row16) * 32 + cslot];
#pragma unroll
    for (int f = 0; f < 4; ++f)
      bf[f] = *(const f16x8*)&sm[b][1][(wn * 64 + f * 16 + row16) * 32 + cslot];
#pragma unroll
    for (int fm = 0; fm < 8; ++fm)
#pragma unroll
      for (int fn = 0; fn < 4; ++fn)
        acc[fm][fn] = __builtin_amdgcn_mfma_f32_16x16x32_f16(bf[fn], af[fm], acc[fm][fn], 0, 0, 0);
    asm volatile("s_barrier" ::: "memory");
  }

  // lane holds m = wm*128+fm*16+row16 ; n = wn*64+fn*16+quad*4+{0..3}
  const int nb = bn * 256 + wn * 64 + quad * 4;
  const float* b1e = b1 + (size_t)e * DFF + nb;
#pragma unroll
  for (int fm = 0; fm < 8; ++fm) {
    int m = bm * 256 + wm * 128 + fm * 16 + row16;
    if (m < count) {
      u16* hr = H + (size_t)(off + m) * DFF + nb;
#pragma unroll
      for (int fn = 0; fn < 4; ++fn) {
        float4 bv = *(const float4*)(b1e + fn * 16);
        union { _Float16 h[4]; uint2 u; } pk;
        float v0 = acc[fm][fn][0] + bv.x; pk.h[0] = (_Float16)(v0 > 0.f ? v0 : 0.f);
        float v1 = acc[fm][fn][1] + bv.y; pk.h[1] = (_Float16)(v1 > 0.f ? v1 : 0.f);
        float v2 = acc[fm][fn][2] + bv.z; pk.h[2] = (_Float16)(v2 > 0.f ? v2 : 0.f);
        float v3 = acc[fm][fn][3] + bv.w; pk.h[3] = (_Float16)(v3 > 0.f ? v3 : 0.f);
        *(uint2*)(hr + fn * 16) = pk.u;
      }
    }
  }
}

// ---------------- GEMM2: P[slot] = H[slot] @ W2 + b2 (fp32, coalesced) -------
__global__ __launch_bounds__(512, 2) void gemm2_kernel(
    const u16* __restrict__ H, const u16* __restrict__ w2t,
    const float* __restrict__ b2,
    const int* __restrict__ counts, const int* __restrict__ offs,
    float* __restrict__ P)
{
  const int e = blockIdx.z;
  const int count = counts[e];
  // grid (4,32,8): XCD = (x+4y)%8 -> each XCD sees a single bn (=x'%4):
  // one 2MB W2 n-panel resident per XCD L2. No remap needed.
  const int bn = blockIdx.x;                        // 0..3
  const int bm = blockIdx.y;                        // 0..31
  if (bm * 256 >= count) return;
  const int off = offs[e];

  __shared__ __align__(16) u16 sm[4][2][8192];   // quad buffer: 128KB, 1 blk/CU

  const int tid = threadIdx.x;
  const int w = tid >> 6, lane = tid & 63;
  const int wm = w >> 2, wn = w & 3;
  const int row16 = lane & 15, quad = lane >> 4;
  const int r = lane >> 2;
  const int cg8 = (((lane & 3) ^ (r & 3)) << 3);
  const int cm1 = count - 1;

  const u16* agA[2]; const u16* agB[2];
#pragma unroll
  for (int j = 0; j < 2; ++j) {
    int m = bm * 256 + w * 32 + j * 16 + r;
    agA[j] = H + (size_t)(off + (m < cm1 ? m : cm1)) * DFF + cg8;
    int nrow = bn * 256 + w * 32 + j * 16 + r;
    agB[j] = w2t + ((size_t)e * DMODEL + nrow) * DFF + cg8;
  }
  const int ldsoff = w * 1024;
  const int cslot = ((quad ^ (row16 & 3)) << 3);

  f32x4 acc[8][4] = {};

  constexpr int NK = DFF / 32;   // 128
  // depth-3: tiles k+1,k+2,k+3 in flight across the wait (12 loads).
  STAGE1(0, 0); STAGE1(1, 1); STAGE1(2, 2);
  for (int k = 0; k < NK; ++k) {
    const int b = k & 3;
    STAGE1((k + 3) & (NK - 1), (k + 3) & 3);   // unconditional: keeps vmcnt exact
    asm volatile("s_waitcnt vmcnt(12)\n\ts_barrier" ::: "memory");
    f16x8 af[8], bf[4];
#pragma unroll
    for (int f = 0; f < 8; ++f)
      af[f] = *(const f16x8*)&sm[b][0][(wm * 128 + f * 16 + row16) * 32 + cslot];
#pragma unroll
    for (int f = 0; f < 4; ++f)
      bf[f] = *(const f16x8*)&sm[b][1][(wn * 64 + f * 16 + row16) * 32 + cslot];
#pragma unroll
    for (int fm = 0; fm < 8; ++fm)
#pragma unroll
      for (int fn = 0; fn < 4; ++fn)
        acc[fm][fn] = __builtin_amdgcn_mfma_f32_16x16x32_f16(bf[fn], af[fm], acc[fm][fn], 0, 0, 0);
    asm volatile("s_barrier" ::: "memory");
  }

  const int nb = bn * 256 + wn * 64 + quad * 4;
  const float* b2e = b2 + (size_t)e * DMODEL + nb;
#pragma unroll
  for (int fm = 0; fm < 8; ++fm) {
    int m = bm * 256 + wm * 128 + fm * 16 + row16;
    if (m < count) {
      float* pr = P + (size_t)(off + m) * DMODEL + nb;
#pragma unroll
      for (int fn = 0; fn < 4; ++fn) {
        float4 bv = *(const float4*)(b2e + fn * 16);
        float4 o;
        o.x = acc[fm][fn][0] + bv.x;
        o.y = acc[fm][fn][1] + bv.y;
        o.z = acc[fm][fn][2] + bv.z;
        o.w = acc[fm][fn][3] + bv.w;
        *(float4*)(pr + fn * 16) = o;
      }
    }
  }
}

// ---------------- combine: out[t] = w0*P[s0] + w1*P[s1] ----------------------
__global__ __launch_bounds__(256) void combine_kernel(
    const float* __restrict__ P, const int* __restrict__ tok_slot,
    const float* __restrict__ tok_w, float* __restrict__ out)
{
  int idx = blockIdx.x * 256 + threadIdx.x;
  int t = idx >> 8;
  int d = (idx & 255) << 2;
  int s0 = tok_slot[2 * t], s1 = tok_slot[2 * t + 1];
  float w0 = tok_w[2 * t], w1 = tok_w[2 * t + 1];
  float4 a = *(const float4*)(P + (size_t)s0 * DMODEL + d);
  float4 b = *(const float4*)(P + (size_t)s1 * DMODEL + d);
  float4 o;
  o.x = w0 * a.x + w1 * b.x;
  o.y = w0 * a.y + w1 * b.y;
  o.z = w0 * a.z + w1 * b.z;
  o.w = w0 * a.w + w1 * b.w;
  *(float4*)(out + (size_t)t * DMODEL + d) = o;
}

// ---------------- launch -----------------------------------------------------
extern "C" void kernel_launch(void* const* d_in, const int* in_sizes, int n_in,
                              void* d_out, int out_size, void* d_ws, size_t ws_size,
                              hipStream_t stream)
{
  const float* x      = (const float*)d_in[0];
  const float* gumbel = (const float*)d_in[1];
  const float* gate_w = (const float*)d_in[2];
  const float* gate_b = (const float*)d_in[3];
  const float* w1     = (const float*)d_in[4];
  const float* b1     = (const float*)d_in[5];
  const float* w2     = (const float*)d_in[6];
  const float* b2     = (const float*)d_in[7];
  float* out = (float*)d_out;
  char* ws = (char*)d_ws;

  // workspace layout (~286 MB; P overlays dead w1t region)
  constexpr size_t OFF_COUNTS = 0;
  constexpr size_t OFF_OFFS   = 64;
  constexpr size_t OFF_TOK    = 4096;
  constexpr size_t OFF_TE     = OFF_TOK + (size_t)NEXP * T_TOKENS * 4;
  constexpr size_t OFF_TP     = OFF_TE + 2 * T_TOKENS * 4;
  constexpr size_t OFF_TW     = OFF_TP + 2 * T_TOKENS * 4;
  constexpr size_t OFF_TS     = OFF_TW + 2 * T_TOKENS * 4;
  constexpr size_t OFF_XH     = OFF_TS + 2 * T_TOKENS * 4;
  constexpr size_t OFF_W1T    = OFF_XH  + (size_t)T_TOKENS * DMODEL * 2;
  constexpr size_t OFF_W2T    = OFF_W1T + (size_t)NEXP * DFF * DMODEL * 2;
  constexpr size_t OFF_H      = OFF_W2T + (size_t)NEXP * DMODEL * DFF * 2;
  constexpr size_t OFF_P      = OFF_W1T;  // w1t dead after gemm1

  int*   counts = (int*)(ws + OFF_COUNTS);
  int*   offs   = (int*)(ws + OFF_OFFS);
  int*   tokl   = (int*)(ws + OFF_TOK);
  int*   tok_e  = (int*)(ws + OFF_TE);
  int*   tok_p  = (int*)(ws + OFF_TP);
  float* tok_w  = (float*)(ws + OFF_TW);
  int*   tok_s  = (int*)(ws + OFF_TS);
  u16*   xh     = (u16*)(ws + OFF_XH);
  u16*   w1t    = (u16*)(ws + OFF_W1T);
  u16*   w2t    = (u16*)(ws + OFF_W2T);
  u16*   H      = (u16*)(ws + OFF_H);
  float* P      = (float*)(ws + OFF_P);

  hipMemsetAsync(ws + OFF_COUNTS, 0, 1024, stream);

  cvt_f16_kernel<<<(T_TOKENS * DMODEL / 4 + 255) / 256, 256, 0, stream>>>(
      x, xh, T_TOKENS * DMODEL / 4);
  transpose_cvt_kernel<<<dim3(DFF / 64, DMODEL / 64, NEXP), 256, 0, stream>>>(
      w1, w1t, DMODEL, DFF);
  transpose_cvt_kernel<<<dim3(DMODEL / 64, DFF / 64, NEXP), 256, 0, stream>>>(
      w2, w2t, DFF, DMODEL);
  gate_kernel<<<T_TOKENS / 4, 256, 0, stream>>>(
      x, gumbel, gate_w, gate_b, counts, tokl, tok_e, tok_p, tok_w);
  offsets_kernel<<<1, 64, 0, stream>>>(counts, offs);
  slots_kernel<<<(2 * T_TOKENS + 255) / 256, 256, 0, stream>>>(
      offs, tok_e, tok_p, tok_s);
  gemm1_kernel<<<dim3(16, 32, NEXP), 512, 0, stream>>>(
      xh, w1t, b1, counts, offs, tokl, H);
  gemm2_kernel<<<dim3(4, 32, NEXP), 512, 0, stream>>>(
      H, w2t, b2, counts, offs, P);
  combine_kernel<<<T_TOKENS, 256, 0, stream>>>(P, tok_s, tok_w, out);
}